// Round 4
// baseline (452.007 us; speedup 1.0000x reference)
//
#include <hip/hip_runtime.h>
#include <hip/hip_bf16.h>

// EdgeGT encoder layer, B=4 N=512 D=64 H=8 HD=8 MULT=4, fp32.
// ws layout (floats): Q[0..128K) K[128K..256K) V[256K..384K) Y[384K..512K)  (2 MiB)

#define SGLD 516   // LDS row stride (floats); 516%32=4 -> <=2-way bank aliasing (free)

typedef float f32x4 __attribute__((ext_vector_type(4)));

// DPP lane exchange within 16-lane rows (pure VALU, no DS pipe).
// 0xB1 = quad_perm(1,0,3,2) = xor1 ; 0x4E = quad_perm(2,3,0,1) = xor2
// 0x141 = row_half_mirror = xor7   ; 0x140 = row_mirror = xor15
template <int CTRL>
__device__ __forceinline__ float dpp_xchg(float x) {
  int xi = __float_as_int(x);
  int r = __builtin_amdgcn_update_dpp(xi, xi, CTRL, 0xF, 0xF, false);
  return __int_as_float(r);
}

// ---------------- Kernel 1: hn = LN1(h); qkv = hn @ W_h ----------------
__global__ __launch_bounds__(256) void qkv_kernel(
    const float* __restrict__ h, const float* __restrict__ Wh,
    const float* __restrict__ g1, const float* __restrict__ b1,
    float* __restrict__ Q, float* __restrict__ K, float* __restrict__ V) {
  int w = threadIdx.x >> 6;
  int lane = threadIdx.x & 63;
  int row = blockIdx.x * 4 + w;           // 0..B*N-1
  __shared__ float hn_s[4][64];
  float x = h[row * 64 + lane];
  float s = x, ss = x * x;
  #pragma unroll
  for (int m = 1; m < 64; m <<= 1) {
    s  += __shfl_xor(s, m);
    ss += __shfl_xor(ss, m);
  }
  float mean = s * (1.0f / 64.0f);
  float var  = ss * (1.0f / 64.0f) - mean * mean;
  float rs   = rsqrtf(var + 1e-5f);
  float hn   = (x - mean) * rs * g1[lane] + b1[lane];
  hn_s[w][lane] = hn;
  __syncthreads();
  float aq = 0.f, ak = 0.f, av = 0.f;
  #pragma unroll 4
  for (int d = 0; d < 64; d++) {
    float hd = hn_s[w][d];
    aq = fmaf(hd, Wh[d * 192 + lane], aq);
    ak = fmaf(hd, Wh[d * 192 + 64 + lane], ak);
    av = fmaf(hd, Wh[d * 192 + 128 + lane], av);
  }
  Q[row * 64 + lane] = aq;
  K[row * 64 + lane] = ak;
  V[row * 64 + lane] = av;
}

// ---------------- Kernel 2: fused e@W_e + biased softmax + gate + PV ----------------
// One block per (b,q). 256 threads = 16 groups of 16 lanes (= DPP rows).
// Group g handles k-rows {it*16+g}. Lane lj owns e-dims [4lj,4lj+4).
// Segmented reduce of 16 per-lane partial outputs -> output j lands on lane j,
// all via DPP (partners xor15,xor7,xor2,xor1 against split bits 3,2,1,0).
// e is streamed with NON-TEMPORAL loads (zero reuse) so K/V/W_e stay L2-resident.
__global__ __launch_bounds__(256, 3) void attn_kernel(
    const float* __restrict__ E, const float* __restrict__ We,
    const float* __restrict__ Q, const float* __restrict__ K,
    const float* __restrict__ V, float* __restrict__ Y) {
  __shared__ float sg[16 * SGLD];     // rows 0..7: logits (then p*gate); rows 8..15: gate
  __shared__ float invl[8];
  __shared__ float ypart[4][64];

  const int t   = threadIdx.x;
  const int lj  = t & 15;
  const int row = blockIdx.x;         // b*N + q
  const int b   = row >> 9;

  // W_e fragment: this lane's 4 input dims x 16 outputs
  float we[4][16];
  #pragma unroll
  for (int i = 0; i < 4; i++)
    #pragma unroll
    for (int j = 0; j < 16; j++)
      we[i][j] = We[(4 * lj + i) * 16 + j];

  f32x4 q4 = *(const f32x4*)(Q + (size_t)row * 64 + 4 * lj);
  const float inv_s8 = 0.35355339059327373f;   // 1/sqrt(HD)
  q4 *= inv_s8;

  const int grp = t >> 4;
  // e pointer in f32x4 units; row stride (16 k-rows * 64 floats) = 256 f32x4
  const f32x4* ep = (const f32x4*)(E + (size_t)row * (512 * 64)) + grp * 16 + lj;
  const f32x4* kp = (const f32x4*)(K + ((size_t)(b << 9) + grp) * 64) + lj;
  float* sgw = sg + lj * SGLD + grp;                 // + it*16 per iter
  // bpermute byte-addr for head-qk broadcast: src lane (in wave) = rowbase + 2*(lj&7)
  const int baddr = 4 * ((t & 48) + 2 * (lj & 7));
  const float e1mask = (lj < 8) ? 1.0f : 0.0f;

  // 2-deep prefetch: a = row(it), b = row(it+1); fetch row(it+2) each iter.
  f32x4 e4a = __builtin_nontemporal_load(ep);
  f32x4 k4a = *kp;
  f32x4 e4b = __builtin_nontemporal_load(ep + 256);
  f32x4 k4b = *(kp + 256);

  for (int it = 0; it < 32; ++it) {
    const int adv2 = (it < 30) ? 512 : 0;            // uniform; clamp at tail
    const f32x4 e4c = __builtin_nontemporal_load(ep + adv2);
    const f32x4 k4c = *(kp + adv2);
    ep += 256; kp += 256;

    float acc[16];
    #pragma unroll
    for (int j = 0; j < 16; j++) {
      acc[j] = fmaf(e4a.x, we[0][j],
               fmaf(e4a.y, we[1][j],
               fmaf(e4a.z, we[2][j], e4a.w * we[3][j])));
    }
    // qk partial over this lane's 4 dims (q prescaled); pair-sum via DPP xor1:
    // lanes 2h,2h+1 then both hold qk of head h (head h = dims [8h,8h+8)).
    float qk = fmaf(q4.x, k4a.x, fmaf(q4.y, k4a.y, fmaf(q4.z, k4a.z, q4.w * k4a.w)));
    qk += dpp_xchg<0xB1>(qk);

    // ---- segmented butterfly, all DPP ----
    float c8[8];
    { const bool hi = (lj & 8) != 0;                 // split bit3, partner xor15
      #pragma unroll
      for (int i = 0; i < 8; i++) {
        float snd = hi ? acc[i]     : acc[i + 8];
        float kp_ = hi ? acc[i + 8] : acc[i];
        c8[i] = kp_ + dpp_xchg<0x140>(snd);
      } }
    float c4v[4];
    { const bool hi = (lj & 4) != 0;                 // split bit2, partner xor7
      #pragma unroll
      for (int i = 0; i < 4; i++) {
        float snd = hi ? c8[i]     : c8[i + 4];
        float kp_ = hi ? c8[i + 4] : c8[i];
        c4v[i] = kp_ + dpp_xchg<0x141>(snd);
      } }
    float c2v[2];
    { const bool hi = (lj & 2) != 0;                 // split bit1, partner xor2
      #pragma unroll
      for (int i = 0; i < 2; i++) {
        float snd = hi ? c4v[i]     : c4v[i + 2];
        float kp_ = hi ? c4v[i + 2] : c4v[i];
        c2v[i] = kp_ + dpp_xchg<0x4E>(snd);
      } }
    float ew;
    { const bool hi = (lj & 1) != 0;                 // split bit0, partner xor1
      float snd = hi ? c2v[0] : c2v[1];
      float kp_ = hi ? c2v[1] : c2v[0];
      ew = kp_ + dpp_xchg<0xB1>(snd);
    }
    // lane lj<8: logit = qk_head(lj) + e1 ; lane lj>=8: gate = e2
    float qk_h = __int_as_float(
        __builtin_amdgcn_ds_bpermute(baddr, __float_as_int(qk)));
    sgw[it * 16] = fmaf(qk_h, e1mask, ew);

    e4a = e4b; k4a = k4b;
    e4b = e4c; k4b = k4c;
  }
  __syncthreads();

  // ---- softmax per head: half-wave (32 lanes) per head ----
  {
    const int wv = t >> 6;
    const int hh = wv * 2 + ((t >> 5) & 1);
    const int sl = t & 31;
    float m = -1e30f;
    #pragma unroll 4
    for (int i = 0; i < 16; i++) m = fmaxf(m, sg[hh * SGLD + sl + 32 * i]);
    #pragma unroll
    for (int mk = 1; mk <= 16; mk <<= 1) m = fmaxf(m, __shfl_xor(m, mk));
    float lsum = 0.f;
    #pragma unroll 4
    for (int i = 0; i < 16; i++) {
      int k = sl + 32 * i;
      float p = __expf(sg[hh * SGLD + k] - m);
      lsum += p;
      sg[hh * SGLD + k] = p * sg[(8 + hh) * SGLD + k];   // p * gate (unnormalized)
    }
    #pragma unroll
    for (int mk = 1; mk <= 16; mk <<= 1) lsum += __shfl_xor(lsum, mk);
    if (sl == 0) invl[hh] = 1.0f / lsum;
  }
  __syncthreads();

  // ---- y[d] = (sum_k pg[h(d)][k] * V[b,k,d]) / l ----
  {
    const int d  = t & 63;
    const int kc = t >> 6;           // 4 chunks of 128 k
    const int hd = d >> 3;
    const float* vb = V + (size_t)((b << 9) + kc * 128) * 64 + d;
    float acc = 0.f;
    #pragma unroll 4
    for (int i = 0; i < 128; i++) {
      acc = fmaf(sg[hd * SGLD + kc * 128 + i], vb[(size_t)i * 64], acc);
    }
    ypart[kc][d] = acc;
  }
  __syncthreads();
  if (t < 64) {
    const int d = t;
    float y = (ypart[0][d] + ypart[1][d] + ypart[2][d] + ypart[3][d]) * invl[d >> 3];
    Y[(size_t)row * 64 + d] = y;
  }
}

// ---------------- Kernel 3: z = LN2(y+h); out = relu(z@W1)@W2 + y ----------------
// 4 rows per block; W1/W2 columns staged in registers (read once per block).
__global__ __launch_bounds__(256) void mlp_kernel(
    const float* __restrict__ Y, const float* __restrict__ Hin,
    const float* __restrict__ W1, const float* __restrict__ W2,
    const float* __restrict__ g2, const float* __restrict__ b2,
    float* __restrict__ out) {
  __shared__ float z_s[4][64];
  __shared__ float t1_s[4][256];
  __shared__ float op[4][4][64];
  const int t = threadIdx.x;
  const int w = t >> 6, l = t & 63;
  const int row0 = blockIdx.x * 4;

  float w1c[64], w2c[64];
  #pragma unroll 8
  for (int d = 0; d < 64; ++d) w1c[d] = W1[d * 256 + t];
  #pragma unroll 8
  for (int i = 0; i < 64; ++i) w2c[i] = W2[(w * 64 + i) * 64 + l];

  {
    int row = row0 + w;
    float x = Y[row * 64 + l] + Hin[row * 64 + l];
    float s = x, ss = x * x;
    #pragma unroll
    for (int m = 1; m < 64; m <<= 1) { s += __shfl_xor(s, m); ss += __shfl_xor(ss, m); }
    float mean = s * (1.0f / 64.0f);
    float var  = ss * (1.0f / 64.0f) - mean * mean;
    z_s[w][l] = (x - mean) * rsqrtf(var + 1e-5f) * g2[l] + b2[l];
  }
  __syncthreads();
  #pragma unroll
  for (int r = 0; r < 4; ++r) {
    float a = 0.f;
    #pragma unroll 8
    for (int d = 0; d < 64; ++d) a = fmaf(z_s[r][d], w1c[d], a);
    t1_s[r][t] = fmaxf(a, 0.f);
  }
  __syncthreads();
  #pragma unroll
  for (int r = 0; r < 4; ++r) {
    float a = 0.f;
    #pragma unroll 8
    for (int i = 0; i < 64; ++i) a = fmaf(t1_s[r][w * 64 + i], w2c[i], a);
    op[r][w][l] = a;
  }
  __syncthreads();
  {
    int row = row0 + w;
    out[row * 64 + l] = Y[row * 64 + l]
        + op[w][0][l] + op[w][1][l] + op[w][2][l] + op[w][3][l];
  }
}

extern "C" void kernel_launch(void* const* d_in, const int* in_sizes, int n_in,
                              void* d_out, int out_size, void* d_ws, size_t ws_size,
                              hipStream_t stream) {
  const float* h  = (const float*)d_in[0];
  const float* e  = (const float*)d_in[1];
  const float* Wh = (const float*)d_in[2];
  const float* We = (const float*)d_in[3];
  const float* W1 = (const float*)d_in[4];
  const float* W2 = (const float*)d_in[5];
  const float* g1 = (const float*)d_in[6];
  const float* b1 = (const float*)d_in[7];
  const float* g2 = (const float*)d_in[8];
  const float* b2 = (const float*)d_in[9];
  float* out = (float*)d_out;
  float* ws  = (float*)d_ws;
  float* Q  = ws;
  float* K  = ws + 131072;
  float* V  = ws + 262144;
  float* Yb = ws + 393216;

  qkv_kernel<<<512, 256, 0, stream>>>(h, Wh, g1, b1, Q, K, V);
  attn_kernel<<<2048, 256, 0, stream>>>(e, We, Q, K, V, Yb);
  mlp_kernel<<<512, 256, 0, stream>>>(Yb, h, W1, W2, g2, b2, out);
}